// Round 6
// baseline (350.375 us; speedup 1.0000x reference)
//
#include <hip/hip_runtime.h>
#include <hip/hip_bf16.h>
#include <math.h>

// AdditiveAttention: B=4, Q=512, K=512, H=256, fp32.
// scores[b,q,k] = sum_h wv_h * tanh(qp + kp) -> softmax_k -> @V
// tanh(x) = 1 - 2/(1+e^{2x}); sum_h wv_h drops out of softmax.
// e^{2(q+k)} = e^{2q} * e^{2k}: exponentiate projections once (proj kernel).
// 4 h-terms share one rcp: sum wv_i/t_i = num/(t0*t1*t2*t3).
//
// Two launches (R4 lesson: grid-barrier fusion => cross-XCD coherence storm).
// R6: phase-1 uses contiguous float2 k-pairs (half the VMEM instrs + addr
// VALU vs k,k+256 scalar pairs) and a fully-unrolled h-loop so the prefetch
// is branch-free and schedulable.

#define B_ 4
#define Q_ 512
#define K_ 512
#define H_ 256
#define QE_ELEMS (B_ * Q_ * H_)           // 524288
#define KE_ELEMS (B_ * H_ * K_)           // 524288

static constexpr float CEXP = 2.8853900817779268f; // 2*log2(e)
static constexpr float LOG2E = 1.4426950408889634f;

// ---------------------------------------------------------------------------
// proj_exp: 256 blocks x 1024 thr. Block = one 64x64 output tile; 4 teams of
// 256 thr each reduce a 64-d quarter (double-buffered LDS, reg prefetch);
// LDS combine -> exp2 -> store.  blocks [0,128): qe; [128,256): ke[b][h][k].
// ---------------------------------------------------------------------------
#define PJ_AS(team, buf, dd, row) smem[(((team)*2 + (buf)) * 16 + (dd)) * 68 + (row)]
#define PJ_SS(team, buf, dd, row) smem[8704 + (((team)*2 + (buf)) * 16 + (dd)) * 68 + (row)]

__global__ __launch_bounds__(1024, 4) void proj_exp(
    const float* __restrict__ queries, const float* __restrict__ keys,
    const float* __restrict__ Wq, const float* __restrict__ Wk,
    float* __restrict__ qe, float* __restrict__ ke)
{
    __shared__ __align__(16) float smem[17408];   // 69632 B

    const int bid = blockIdx.x;
    const int team = threadIdx.x >> 8;   // d-quarter 0..3 (64 d each)
    const int tid = threadIdx.x & 255;

    const float* A; const float* S; float* C; int ldc;
    if (bid < 128) {                 // qe: [B*Q=2048 x H=256], 32x4 tiles
        int mt = bid >> 2, nt = bid & 3;
        A = queries + (mt * 64) * H_;
        S = Wq + (nt * 64) * H_;
        C = qe + (mt * 64) * H_ + nt * 64;
        ldc = H_;
    } else {                         // ke: per-b [H=256 x K=512], 4x8 tiles
        int id = bid - 128;
        int b = id >> 5, mt = (id >> 3) & 3, nt = id & 7;
        A = Wk + (mt * 64) * H_;
        S = keys + ((long)(b * K_ + nt * 64)) * H_;
        C = ke + ((long)(b * H_ + mt * 64)) * K_ + nt * 64;
        ldc = K_;
    }

    const int tx = tid & 15;         // n0 = tx*4
    const int ty = tid >> 4;         // m0 = ty*4
    const int ldr = tid >> 2;        // staging row 0..63
    const int ldd = (tid & 3) * 4;   // staging d-offset 0,4,8,12
    const float* GA = A + ldr * H_ + team * 64 + ldd;
    const float* GS = S + ldr * H_ + team * 64 + ldd;

    float4 av = *(const float4*)GA;
    float4 sv = *(const float4*)GS;
    PJ_AS(team, 0, ldd + 0, ldr) = av.x; PJ_AS(team, 0, ldd + 1, ldr) = av.y;
    PJ_AS(team, 0, ldd + 2, ldr) = av.z; PJ_AS(team, 0, ldd + 3, ldr) = av.w;
    PJ_SS(team, 0, ldd + 0, ldr) = sv.x; PJ_SS(team, 0, ldd + 1, ldr) = sv.y;
    PJ_SS(team, 0, ldd + 2, ldr) = sv.z; PJ_SS(team, 0, ldd + 3, ldr) = sv.w;

    float acc[4][4] = {};
#pragma unroll
    for (int c = 0; c < 4; ++c) {    // 4 chunks x 16 d = 64 d per team
        const int cur = c & 1;
        if (c < 3) {                 // register prefetch of next chunk
            av = *(const float4*)(GA + (c + 1) * 16);
            sv = *(const float4*)(GS + (c + 1) * 16);
        }
        __syncthreads();             // buf[cur] writes visible
#pragma unroll
        for (int dd = 0; dd < 16; ++dd) {
            float4 a4 = *(const float4*)&PJ_AS(team, cur, dd, ty * 4);
            float4 b4 = *(const float4*)&PJ_SS(team, cur, dd, tx * 4);
            float am[4] = {a4.x, a4.y, a4.z, a4.w};
            float bn[4] = {b4.x, b4.y, b4.z, b4.w};
#pragma unroll
            for (int i = 0; i < 4; ++i)
#pragma unroll
                for (int j = 0; j < 4; ++j)
                    acc[i][j] = fmaf(am[i], bn[j], acc[i][j]);
        }
        if (c < 3) {                 // fill other buffer (last read 2 iters ago)
            const int nxt = cur ^ 1;
            PJ_AS(team, nxt, ldd + 0, ldr) = av.x;
            PJ_AS(team, nxt, ldd + 1, ldr) = av.y;
            PJ_AS(team, nxt, ldd + 2, ldr) = av.z;
            PJ_AS(team, nxt, ldd + 3, ldr) = av.w;
            PJ_SS(team, nxt, ldd + 0, ldr) = sv.x;
            PJ_SS(team, nxt, ldd + 1, ldr) = sv.y;
            PJ_SS(team, nxt, ldd + 2, ldr) = sv.z;
            PJ_SS(team, nxt, ldd + 3, ldr) = sv.w;
        }
    }

    // combine 4 d-quarter partials via LDS (reuse staging), exp, store
    __syncthreads();                 // all staging reads complete
    if (team > 0) {
        float* Cmb = smem + (team - 1) * 4352;   // 64 x 68 tile
#pragma unroll
        for (int i = 0; i < 4; ++i) {
            float4 o = {acc[i][0], acc[i][1], acc[i][2], acc[i][3]};
            *(float4*)&Cmb[(ty * 4 + i) * 68 + tx * 4] = o;
        }
    }
    __syncthreads();
    if (team == 0) {
#pragma unroll
        for (int i = 0; i < 4; ++i) {
            const int off = (ty * 4 + i) * 68 + tx * 4;
            float4 p1 = *(const float4*)&smem[off];
            float4 p2 = *(const float4*)&smem[4352 + off];
            float4 p3 = *(const float4*)&smem[8704 + off];
            float4 o;
            o.x = __builtin_amdgcn_exp2f(CEXP * (acc[i][0] + p1.x + p2.x + p3.x));
            o.y = __builtin_amdgcn_exp2f(CEXP * (acc[i][1] + p1.y + p2.y + p3.y));
            o.z = __builtin_amdgcn_exp2f(CEXP * (acc[i][2] + p1.z + p2.z + p3.z));
            o.w = __builtin_amdgcn_exp2f(CEXP * (acc[i][3] + p1.w + p2.w + p3.w));
            *(float4*)&C[(ty * 4 + i) * ldc + tx * 4] = o;
        }
    }
}

// ---------------------------------------------------------------------------
// attn: 512 blocks x 1024 thr (16 waves; VGPR<=64 => 2 blocks/CU).
// XCD-affine: bid%8 -> XCD; XCD pair {2b,2b+1} serves batch b, so the hot set
// ke[b]+values[b] (~1MB) stays in that XCD's 4MB L2 (R5: FETCH 17->5MB).
// Phase 1: thread = (k-pair (t&255)*2 -> {k,k+1}, h-quarter t>>8); 4 q rows;
//          quad-rcp; float2 ke loads; fully-unrolled h-loop w/ lookahead.
// Phase 2: softmax, wave w<4 -> q row w.
// Phase 3: thread = (4 h, q, k-quarter); float4 V loads; LDS reduce.
// ---------------------------------------------------------------------------
__global__ __launch_bounds__(1024, 8) void attn(
    const float* __restrict__ qe, const float* __restrict__ ke,
    const float* __restrict__ values, const float* __restrict__ wv,
    float* __restrict__ out)
{
    const int bid = blockIdx.x;
    const int xcd = bid & 7;
    const int b = xcd >> 1;
    const int q0 = (((bid >> 3) << 1) | (xcd & 1)) * 4;
    const int t = threadIdx.x;

    // flat LDS: sQ[4*256] | wvs[256] | sS[4*512] | sP[3][4*512]  (37.9 KB)
    __shared__ __align__(16) float smem[9472];
    float* sQ  = smem;                   // [4][H_]
    float* wvs = smem + 4 * H_;          // [H_]
    float* sS  = smem + 5 * H_;          // [4][K_]
    float* sP  = smem + 5 * H_ + 4 * K_; // [3][4][K_]

    sQ[t] = qe[((long)(b * Q_ + q0 + (t >> 8))) * H_ + (t & 255)];
    if (t < H_) wvs[t] = wv[t];
    __syncthreads();

    // ---- Phase 1: scores
    {
        const int k2 = (t & 255) * 2;    // owns k2, k2+1 (contiguous)
        const int g = t >> 8;            // h-quarter: h in [g*64, g*64+64)
        const float* keb = ke + ((long)(b * H_ + g * 64)) * K_ + k2;

        float2 nx[4];
#pragma unroll
        for (int j = 0; j < 4; ++j) nx[j] = *(const float2*)(keb + j * K_);
        float2 acc[4] = {};              // acc[q]: .x for k2, .y for k2+1

#pragma unroll
        for (int hl = 0; hl < 64; hl += 4) {
            float2 c0 = nx[0], c1 = nx[1], c2 = nx[2], c3 = nx[3];
            if (hl < 60) {               // compile-time guard (full unroll)
                const float* p = keb + (hl + 4) * K_;
                nx[0] = *(const float2*)(p);
                nx[1] = *(const float2*)(p + K_);
                nx[2] = *(const float2*)(p + 2 * K_);
                nx[3] = *(const float2*)(p + 3 * K_);
            }
            const int h = g * 64 + hl;
            float4 w4 = *(const float4*)&wvs[h];
#pragma unroll
            for (int q = 0; q < 4; ++q) {
                float4 e = *(const float4*)&sQ[q * H_ + h];
                {   // kk = 0 (.x lane)
                    float t0 = fmaf(e.x, c0.x, 1.0f);
                    float t1 = fmaf(e.y, c1.x, 1.0f);
                    float t2 = fmaf(e.z, c2.x, 1.0f);
                    float t3 = fmaf(e.w, c3.x, 1.0f);
                    float d01 = t0 * t1, d23 = t2 * t3;
                    float n01 = fmaf(w4.x, t1, w4.y * t0);
                    float n23 = fmaf(w4.z, t3, w4.w * t2);
                    float num = fmaf(n01, d23, n23 * d01);
                    acc[q].x = fmaf(num, __builtin_amdgcn_rcpf(d01 * d23), acc[q].x);
                }
                {   // kk = 1 (.y lane)
                    float t0 = fmaf(e.x, c0.y, 1.0f);
                    float t1 = fmaf(e.y, c1.y, 1.0f);
                    float t2 = fmaf(e.z, c2.y, 1.0f);
                    float t3 = fmaf(e.w, c3.y, 1.0f);
                    float d01 = t0 * t1, d23 = t2 * t3;
                    float n01 = fmaf(w4.x, t1, w4.y * t0);
                    float n23 = fmaf(w4.z, t3, w4.w * t2);
                    float num = fmaf(n01, d23, n23 * d01);
                    acc[q].y = fmaf(num, __builtin_amdgcn_rcpf(d01 * d23), acc[q].y);
                }
            }
        }

        if (g > 0) {
            float* dst = sP + (g - 1) * 4 * K_;
#pragma unroll
            for (int q = 0; q < 4; ++q)
                *(float2*)&dst[q * K_ + k2] = acc[q];
        }
        __syncthreads();
        if (g == 0) {
#pragma unroll
            for (int q = 0; q < 4; ++q) {
                float2 p0 = *(const float2*)&sP[0 * 4 * K_ + q * K_ + k2];
                float2 p1 = *(const float2*)&sP[1 * 4 * K_ + q * K_ + k2];
                float2 p2 = *(const float2*)&sP[2 * 4 * K_ + q * K_ + k2];
                float2 o;
                o.x = -2.0f * (acc[q].x + p0.x + p1.x + p2.x);
                o.y = -2.0f * (acc[q].y + p0.y + p1.y + p2.y);
                *(float2*)&sS[q * K_ + k2] = o;
            }
        }
    }
    __syncthreads();

    // ---- Phase 2: softmax, wave w (w<4) -> q row w
    if (t < 256) {
        const int lane = t & 63;
        const int q = t >> 6;
        float sv[8];
        float m = -INFINITY;
#pragma unroll
        for (int j = 0; j < 8; ++j) {
            sv[j] = sS[q * K_ + lane + 64 * j];
            m = fmaxf(m, sv[j]);
        }
#pragma unroll
        for (int off = 32; off >= 1; off >>= 1) m = fmaxf(m, __shfl_xor(m, off));
        float sum = 0.f;
#pragma unroll
        for (int j = 0; j < 8; ++j) {
            sv[j] = __builtin_amdgcn_exp2f((sv[j] - m) * LOG2E);
            sum += sv[j];
        }
#pragma unroll
        for (int off = 32; off >= 1; off >>= 1) sum += __shfl_xor(sum, off);
        float rs = 1.0f / sum;
#pragma unroll
        for (int j = 0; j < 8; ++j) sS[q * K_ + lane + 64 * j] = sv[j] * rs;
    }
    __syncthreads();

    // ---- Phase 3: attn @ V. thread = (h4, q, k-quarter)
    {
        const int lane = t & 63;
        const int h4 = lane * 4;
        const int q = (t >> 6) & 3;
        const int kq = t >> 8;
        const float* vb = values + (long)b * K_ * H_ + h4;
        const float* sSq = sS + q * K_;
        float4 acc = {0.f, 0.f, 0.f, 0.f};
        const int kbeg = kq * 128;
#pragma unroll 2
        for (int k = kbeg; k < kbeg + 128; k += 4) {
            float4 a = *(const float4*)&sSq[k];
            float4 v0 = *(const float4*)&vb[(k + 0) * H_];
            float4 v1 = *(const float4*)&vb[(k + 1) * H_];
            float4 v2 = *(const float4*)&vb[(k + 2) * H_];
            float4 v3 = *(const float4*)&vb[(k + 3) * H_];
            acc.x = fmaf(a.x, v0.x, fmaf(a.y, v1.x, fmaf(a.z, v2.x, fmaf(a.w, v3.x, acc.x))));
            acc.y = fmaf(a.x, v0.y, fmaf(a.y, v1.y, fmaf(a.z, v2.y, fmaf(a.w, v3.y, acc.y))));
            acc.z = fmaf(a.x, v0.z, fmaf(a.y, v1.z, fmaf(a.z, v2.z, fmaf(a.w, v3.z, acc.z))));
            acc.w = fmaf(a.x, v0.w, fmaf(a.y, v1.w, fmaf(a.z, v2.w, fmaf(a.w, v3.w, acc.w))));
        }
        __syncthreads();   // all sS reads done; reuse sS+sP as reduction buffer
        float4* sRed = (float4*)sS;
        if (kq) sRed[(kq - 1) * 256 + q * 64 + lane] = acc;
        __syncthreads();
        if (kq == 0) {
            float4 p1 = sRed[q * 64 + lane];
            float4 p2 = sRed[256 + q * 64 + lane];
            float4 p3 = sRed[512 + q * 64 + lane];
            acc.x += p1.x + p2.x + p3.x;
            acc.y += p1.y + p2.y + p3.y;
            acc.z += p1.z + p2.z + p3.z;
            acc.w += p1.w + p2.w + p3.w;
            *(float4*)&out[((long)(b * Q_ + q0 + q)) * H_ + h4] = acc;
        }
    }
}

extern "C" void kernel_launch(void* const* d_in, const int* in_sizes, int n_in,
                              void* d_out, int out_size, void* d_ws, size_t ws_size,
                              hipStream_t stream) {
    const float* queries = (const float*)d_in[0];  // [B,Q,H]
    const float* keys    = (const float*)d_in[1];  // [B,K,H]
    const float* values  = (const float*)d_in[2];  // [B,K,H]
    const float* Wq      = (const float*)d_in[3];  // [H,H]
    const float* Wk      = (const float*)d_in[4];  // [H,H]
    const float* wv      = (const float*)d_in[5];  // [H]
    float* out = (float*)d_out;

    // ws: [qe 2MB][ke 2MB]
    float* qe = (float*)d_ws;
    float* ke = qe + QE_ELEMS;

    proj_exp<<<256, 1024, 0, stream>>>(queries, keys, Wq, Wk, qe, ke);
    attn<<<512, 1024, 0, stream>>>(qe, ke, values, wv, out);
}

// Round 7
// 131.969 us; speedup vs baseline: 2.6550x; 2.6550x over previous
//
#include <hip/hip_runtime.h>
#include <hip/hip_bf16.h>
#include <math.h>

// AdditiveAttention: B=4, Q=512, K=512, H=256, fp32.
// scores[b,q,k] = sum_h wv_h * tanh(qp + kp) -> softmax_k -> @V
// tanh(x) = 1 - 2/(1+e^{2x}); sum_h wv_h drops out of softmax.
// e^{2(q+k)} = e^{2q} * e^{2k}: exponentiate projections once (proj kernel).
// 4 h-terms share one rcp: sum wv_i/t_i = num/(t0*t1*t2*t3).
//
// R4 lesson: grid-barrier fusion => cross-XCD coherence storm. Two launches.
// R6 lesson: full unroll + reg prefetch + VGPR<=64 cap => scratch spill storm
//            (FETCH 410MB). Keep runtime loop + shallow prefetch.
// R7: float2 k-pair loads + float2-packed inner math (v_pk_fma_f32 pattern).

#define B_ 4
#define Q_ 512
#define K_ 512
#define H_ 256
#define QE_ELEMS (B_ * Q_ * H_)           // 524288
#define KE_ELEMS (B_ * H_ * K_)           // 524288

static constexpr float CEXP = 2.8853900817779268f; // 2*log2(e)
static constexpr float LOG2E = 1.4426950408889634f;

__device__ __forceinline__ float2 pk_fma(float2 a, float2 b, float2 c) {
    return make_float2(fmaf(a.x, b.x, c.x), fmaf(a.y, b.y, c.y));
}
__device__ __forceinline__ float2 pk_mul(float2 a, float2 b) {
    return make_float2(a.x * b.x, a.y * b.y);
}
__device__ __forceinline__ float2 bc2(float s) { return make_float2(s, s); }

// ---------------------------------------------------------------------------
// proj_exp: 256 blocks x 1024 thr. Block = one 64x64 output tile; 4 teams of
// 256 thr each reduce a 64-d quarter (double-buffered LDS, reg prefetch);
// LDS combine -> exp2 -> store.  blocks [0,128): qe; [128,256): ke[b][h][k].
// ---------------------------------------------------------------------------
#define PJ_AS(team, buf, dd, row) smem[(((team)*2 + (buf)) * 16 + (dd)) * 68 + (row)]
#define PJ_SS(team, buf, dd, row) smem[8704 + (((team)*2 + (buf)) * 16 + (dd)) * 68 + (row)]

__global__ __launch_bounds__(1024, 4) void proj_exp(
    const float* __restrict__ queries, const float* __restrict__ keys,
    const float* __restrict__ Wq, const float* __restrict__ Wk,
    float* __restrict__ qe, float* __restrict__ ke)
{
    __shared__ __align__(16) float smem[17408];   // 69632 B

    const int bid = blockIdx.x;
    const int team = threadIdx.x >> 8;   // d-quarter 0..3 (64 d each)
    const int tid = threadIdx.x & 255;

    const float* A; const float* S; float* C; int ldc;
    if (bid < 128) {                 // qe: [B*Q=2048 x H=256], 32x4 tiles
        int mt = bid >> 2, nt = bid & 3;
        A = queries + (mt * 64) * H_;
        S = Wq + (nt * 64) * H_;
        C = qe + (mt * 64) * H_ + nt * 64;
        ldc = H_;
    } else {                         // ke: per-b [H=256 x K=512], 4x8 tiles
        int id = bid - 128;
        int b = id >> 5, mt = (id >> 3) & 3, nt = id & 7;
        A = Wk + (mt * 64) * H_;
        S = keys + ((long)(b * K_ + nt * 64)) * H_;
        C = ke + ((long)(b * H_ + mt * 64)) * K_ + nt * 64;
        ldc = K_;
    }

    const int tx = tid & 15;         // n0 = tx*4
    const int ty = tid >> 4;         // m0 = ty*4
    const int ldr = tid >> 2;        // staging row 0..63
    const int ldd = (tid & 3) * 4;   // staging d-offset 0,4,8,12
    const float* GA = A + ldr * H_ + team * 64 + ldd;
    const float* GS = S + ldr * H_ + team * 64 + ldd;

    float4 av = *(const float4*)GA;
    float4 sv = *(const float4*)GS;
    PJ_AS(team, 0, ldd + 0, ldr) = av.x; PJ_AS(team, 0, ldd + 1, ldr) = av.y;
    PJ_AS(team, 0, ldd + 2, ldr) = av.z; PJ_AS(team, 0, ldd + 3, ldr) = av.w;
    PJ_SS(team, 0, ldd + 0, ldr) = sv.x; PJ_SS(team, 0, ldd + 1, ldr) = sv.y;
    PJ_SS(team, 0, ldd + 2, ldr) = sv.z; PJ_SS(team, 0, ldd + 3, ldr) = sv.w;

    float acc[4][4] = {};
#pragma unroll
    for (int c = 0; c < 4; ++c) {    // 4 chunks x 16 d = 64 d per team
        const int cur = c & 1;
        if (c < 3) {                 // register prefetch of next chunk
            av = *(const float4*)(GA + (c + 1) * 16);
            sv = *(const float4*)(GS + (c + 1) * 16);
        }
        __syncthreads();             // buf[cur] writes visible
#pragma unroll
        for (int dd = 0; dd < 16; ++dd) {
            float4 a4 = *(const float4*)&PJ_AS(team, cur, dd, ty * 4);
            float4 b4 = *(const float4*)&PJ_SS(team, cur, dd, tx * 4);
            float am[4] = {a4.x, a4.y, a4.z, a4.w};
            float bn[4] = {b4.x, b4.y, b4.z, b4.w};
#pragma unroll
            for (int i = 0; i < 4; ++i)
#pragma unroll
                for (int j = 0; j < 4; ++j)
                    acc[i][j] = fmaf(am[i], bn[j], acc[i][j]);
        }
        if (c < 3) {                 // fill other buffer (last read 2 iters ago)
            const int nxt = cur ^ 1;
            PJ_AS(team, nxt, ldd + 0, ldr) = av.x;
            PJ_AS(team, nxt, ldd + 1, ldr) = av.y;
            PJ_AS(team, nxt, ldd + 2, ldr) = av.z;
            PJ_AS(team, nxt, ldd + 3, ldr) = av.w;
            PJ_SS(team, nxt, ldd + 0, ldr) = sv.x;
            PJ_SS(team, nxt, ldd + 1, ldr) = sv.y;
            PJ_SS(team, nxt, ldd + 2, ldr) = sv.z;
            PJ_SS(team, nxt, ldd + 3, ldr) = sv.w;
        }
    }

    // combine 4 d-quarter partials via LDS (reuse staging), exp, store
    __syncthreads();                 // all staging reads complete
    if (team > 0) {
        float* Cmb = smem + (team - 1) * 4352;   // 64 x 68 tile
#pragma unroll
        for (int i = 0; i < 4; ++i) {
            float4 o = {acc[i][0], acc[i][1], acc[i][2], acc[i][3]};
            *(float4*)&Cmb[(ty * 4 + i) * 68 + tx * 4] = o;
        }
    }
    __syncthreads();
    if (team == 0) {
#pragma unroll
        for (int i = 0; i < 4; ++i) {
            const int off = (ty * 4 + i) * 68 + tx * 4;
            float4 p1 = *(const float4*)&smem[off];
            float4 p2 = *(const float4*)&smem[4352 + off];
            float4 p3 = *(const float4*)&smem[8704 + off];
            float4 o;
            o.x = __builtin_amdgcn_exp2f(CEXP * (acc[i][0] + p1.x + p2.x + p3.x));
            o.y = __builtin_amdgcn_exp2f(CEXP * (acc[i][1] + p1.y + p2.y + p3.y));
            o.z = __builtin_amdgcn_exp2f(CEXP * (acc[i][2] + p1.z + p2.z + p3.z));
            o.w = __builtin_amdgcn_exp2f(CEXP * (acc[i][3] + p1.w + p2.w + p3.w));
            *(float4*)&C[(ty * 4 + i) * ldc + tx * 4] = o;
        }
    }
}

// ---------------------------------------------------------------------------
// attn: 512 blocks x 1024 thr (16 waves; VGPR<=64 => 2 blocks/CU).
// XCD-affine: bid%8 -> XCD; XCD pair {2b,2b+1} serves batch b, so the hot set
// ke[b]+values[b] (~1MB) stays in that XCD's 4MB L2 (R5: FETCH 17->5MB).
// Phase 1: thread = (k-pair (t&255)*2, h-quarter t>>8); 4 q rows; quad-rcp;
//          float2 ke loads; runtime loop, unroll 2, depth-1 prefetch;
//          kk lanes computed as float2 (v_pk_fma_f32 SLP pattern).
// Phase 2: softmax, wave w<4 -> q row w.
// Phase 3: thread = (4 h, q, k-quarter); float4 V loads; LDS reduce.
// ---------------------------------------------------------------------------
__global__ __launch_bounds__(1024, 8) void attn(
    const float* __restrict__ qe, const float* __restrict__ ke,
    const float* __restrict__ values, const float* __restrict__ wv,
    float* __restrict__ out)
{
    const int bid = blockIdx.x;
    const int xcd = bid & 7;
    const int b = xcd >> 1;
    const int q0 = (((bid >> 3) << 1) | (xcd & 1)) * 4;
    const int t = threadIdx.x;

    // flat LDS: sQ[4*256] | wvs[256] | sS[4*512] | sP[3][4*512]  (37.9 KB)
    __shared__ __align__(16) float smem[9472];
    float* sQ  = smem;                   // [4][H_]
    float* wvs = smem + 4 * H_;          // [H_]
    float* sS  = smem + 5 * H_;          // [4][K_]
    float* sP  = smem + 5 * H_ + 4 * K_; // [3][4][K_]

    sQ[t] = qe[((long)(b * Q_ + q0 + (t >> 8))) * H_ + (t & 255)];
    if (t < H_) wvs[t] = wv[t];
    __syncthreads();

    // ---- Phase 1: scores
    {
        const int k2 = (t & 255) * 2;    // owns k2, k2+1 (contiguous)
        const int g = t >> 8;            // h-quarter: h in [g*64, g*64+64)
        const float* keb = ke + ((long)(b * H_ + g * 64)) * K_ + k2;

        float2 nx0 = *(const float2*)(keb);
        float2 nx1 = *(const float2*)(keb + K_);
        float2 nx2 = *(const float2*)(keb + 2 * K_);
        float2 nx3 = *(const float2*)(keb + 3 * K_);
        float2 acc[4] = {};              // acc[q]: .x k2, .y k2+1
        const float2 one2 = {1.0f, 1.0f};

#pragma unroll 2
        for (int hl = 0; hl < 64; hl += 4) {
            float2 c0 = nx0, c1 = nx1, c2 = nx2, c3 = nx3;
            if (hl < 60) {               // depth-1 prefetch (runtime guard)
                const float* p = keb + (hl + 4) * K_;
                nx0 = *(const float2*)(p);
                nx1 = *(const float2*)(p + K_);
                nx2 = *(const float2*)(p + 2 * K_);
                nx3 = *(const float2*)(p + 3 * K_);
            }
            const int h = g * 64 + hl;
            float4 w4 = *(const float4*)&wvs[h];
#pragma unroll
            for (int q = 0; q < 4; ++q) {
                float4 e = *(const float4*)&sQ[q * H_ + h];
                float2 t0 = pk_fma(bc2(e.x), c0, one2);
                float2 t1 = pk_fma(bc2(e.y), c1, one2);
                float2 t2 = pk_fma(bc2(e.z), c2, one2);
                float2 t3 = pk_fma(bc2(e.w), c3, one2);
                float2 d01 = pk_mul(t0, t1);
                float2 d23 = pk_mul(t2, t3);
                float2 n01 = pk_fma(bc2(w4.x), t1, pk_mul(bc2(w4.y), t0));
                float2 n23 = pk_fma(bc2(w4.z), t3, pk_mul(bc2(w4.w), t2));
                float2 num = pk_fma(n01, d23, pk_mul(n23, d01));
                float2 den = pk_mul(d01, d23);
                acc[q].x = fmaf(num.x, __builtin_amdgcn_rcpf(den.x), acc[q].x);
                acc[q].y = fmaf(num.y, __builtin_amdgcn_rcpf(den.y), acc[q].y);
            }
        }

        if (g > 0) {
            float* dst = sP + (g - 1) * 4 * K_;
#pragma unroll
            for (int q = 0; q < 4; ++q)
                *(float2*)&dst[q * K_ + k2] = acc[q];
        }
        __syncthreads();
        if (g == 0) {
#pragma unroll
            for (int q = 0; q < 4; ++q) {
                float2 p0 = *(const float2*)&sP[0 * 4 * K_ + q * K_ + k2];
                float2 p1 = *(const float2*)&sP[1 * 4 * K_ + q * K_ + k2];
                float2 p2 = *(const float2*)&sP[2 * 4 * K_ + q * K_ + k2];
                float2 o;
                o.x = -2.0f * (acc[q].x + p0.x + p1.x + p2.x);
                o.y = -2.0f * (acc[q].y + p0.y + p1.y + p2.y);
                *(float2*)&sS[q * K_ + k2] = o;
            }
        }
    }
    __syncthreads();

    // ---- Phase 2: softmax, wave w (w<4) -> q row w
    if (t < 256) {
        const int lane = t & 63;
        const int q = t >> 6;
        float sv[8];
        float m = -INFINITY;
#pragma unroll
        for (int j = 0; j < 8; ++j) {
            sv[j] = sS[q * K_ + lane + 64 * j];
            m = fmaxf(m, sv[j]);
        }
#pragma unroll
        for (int off = 32; off >= 1; off >>= 1) m = fmaxf(m, __shfl_xor(m, off));
        float sum = 0.f;
#pragma unroll
        for (int j = 0; j < 8; ++j) {
            sv[j] = __builtin_amdgcn_exp2f((sv[j] - m) * LOG2E);
            sum += sv[j];
        }
#pragma unroll
        for (int off = 32; off >= 1; off >>= 1) sum += __shfl_xor(sum, off);
        float rs = 1.0f / sum;
#pragma unroll
        for (int j = 0; j < 8; ++j) sS[q * K_ + lane + 64 * j] = sv[j] * rs;
    }
    __syncthreads();

    // ---- Phase 3: attn @ V. thread = (h4, q, k-quarter)
    {
        const int lane = t & 63;
        const int h4 = lane * 4;
        const int q = (t >> 6) & 3;
        const int kq = t >> 8;
        const float* vb = values + (long)b * K_ * H_ + h4;
        const float* sSq = sS + q * K_;
        float4 acc = {0.f, 0.f, 0.f, 0.f};
        const int kbeg = kq * 128;
#pragma unroll 2
        for (int k = kbeg; k < kbeg + 128; k += 4) {
            float4 a = *(const float4*)&sSq[k];
            float4 v0 = *(const float4*)&vb[(k + 0) * H_];
            float4 v1 = *(const float4*)&vb[(k + 1) * H_];
            float4 v2 = *(const float4*)&vb[(k + 2) * H_];
            float4 v3 = *(const float4*)&vb[(k + 3) * H_];
            acc.x = fmaf(a.x, v0.x, fmaf(a.y, v1.x, fmaf(a.z, v2.x, fmaf(a.w, v3.x, acc.x))));
            acc.y = fmaf(a.x, v0.y, fmaf(a.y, v1.y, fmaf(a.z, v2.y, fmaf(a.w, v3.y, acc.y))));
            acc.z = fmaf(a.x, v0.z, fmaf(a.y, v1.z, fmaf(a.z, v2.z, fmaf(a.w, v3.z, acc.z))));
            acc.w = fmaf(a.x, v0.w, fmaf(a.y, v1.w, fmaf(a.z, v2.w, fmaf(a.w, v3.w, acc.w))));
        }
        __syncthreads();   // all sS reads done; reuse sS+sP as reduction buffer
        float4* sRed = (float4*)sS;
        if (kq) sRed[(kq - 1) * 256 + q * 64 + lane] = acc;
        __syncthreads();
        if (kq == 0) {
            float4 p1 = sRed[q * 64 + lane];
            float4 p2 = sRed[256 + q * 64 + lane];
            float4 p3 = sRed[512 + q * 64 + lane];
            acc.x += p1.x + p2.x + p3.x;
            acc.y += p1.y + p2.y + p3.y;
            acc.z += p1.z + p2.z + p3.z;
            acc.w += p1.w + p2.w + p3.w;
            *(float4*)&out[((long)(b * Q_ + q0 + q)) * H_ + h4] = acc;
        }
    }
}

extern "C" void kernel_launch(void* const* d_in, const int* in_sizes, int n_in,
                              void* d_out, int out_size, void* d_ws, size_t ws_size,
                              hipStream_t stream) {
    const float* queries = (const float*)d_in[0];  // [B,Q,H]
    const float* keys    = (const float*)d_in[1];  // [B,K,H]
    const float* values  = (const float*)d_in[2];  // [B,K,H]
    const float* Wq      = (const float*)d_in[3];  // [H,H]
    const float* Wk      = (const float*)d_in[4];  // [H,H]
    const float* wv      = (const float*)d_in[5];  // [H]
    float* out = (float*)d_out;

    // ws: [qe 2MB][ke 2MB]
    float* qe = (float*)d_ws;
    float* ke = qe + QE_ELEMS;

    proj_exp<<<256, 1024, 0, stream>>>(queries, keys, Wq, Wk, qe, ke);
    attn<<<512, 1024, 0, stream>>>(qe, ke, values, wv, out);
}